// Round 2
// baseline (2564.004 us; speedup 1.0000x reference)
//
#include <hip/hip_runtime.h>
#include <hip/hip_bf16.h>
#include <math.h>

#define NR 32768
#define DD 384
#define CDM 882
#define CDMP 896

typedef float f4 __attribute__((ext_vector_type(4)));
typedef float f32x4 __attribute__((ext_vector_type(4)));
typedef __bf16 bf16x8 __attribute__((ext_vector_type(8)));
typedef __bf16 bf16x4 __attribute__((ext_vector_type(4)));

__device__ inline f4 ld4(const float* p) { f4 v; __builtin_memcpy(&v, p, 16); return v; }
__device__ inline void st4(float* p, f4 v) { __builtin_memcpy(p, &v, 16); }
__device__ inline bf16x8 ld8h(const __bf16* p) { bf16x8 v; __builtin_memcpy(&v, p, 16); return v; }
__device__ inline void st8h(__bf16* p, bf16x8 v) { __builtin_memcpy(p, &v, 16); }

__device__ inline void gl_lds16(const void* g, void* l) {
  __builtin_amdgcn_global_load_lds(
      (const __attribute__((address_space(1))) void*)g,
      (__attribute__((address_space(3))) void*)l, 16, 0, 0);
}

__device__ inline float gred16(float v) {
#pragma unroll
  for (int o = 1; o < 16; o <<= 1) v += __shfl_xor(v, o, 64);
  return v;
}

// ---------------- weight transposes (fused) ----------------
struct WPtrs { const float* w[18]; };

__global__ __launch_bounds__(256) void trans_all_k(WPtrs P, __bf16* __restrict__ dst) {
  int wi = blockIdx.y;
  const float* W = P.w[wi];
  __bf16* WT = dst + (size_t)wi * DD * DD;
  int i = blockIdx.x * 256 + threadIdx.x;
  if (i >= DD * DD) return;
  int n = i / DD, k = i - n * DD;
  WT[i] = (__bf16)W[(size_t)k * DD + n];
}

__global__ __launch_bounds__(256) void trans_corr_k(const float* __restrict__ W,
                                                    __bf16* __restrict__ WT) {
  int i = blockIdx.x * 256 + threadIdx.x;
  if (i >= DD * CDMP) return;
  int n = i / CDMP, k = i - n * CDMP;
  WT[i] = (k < CDM) ? (__bf16)W[(size_t)k * DD + n] : (__bf16)0.f;
}

// ---------------- MFMA GEMM: OUT[M,384] = epi(A[M,K] @ W) ----------------
// EPI: 0 store, 1 relu, 2 OUT += v (in-place), 3 OUT = XRES + sigmoid(OUT)*v
// AFP32: A is fp32 (reg-stage + convert); else bf16 via global_load_lds.
// LDS tiles [128][64] bf16, chunk(16B)-XOR swizzle: pos chunk = c ^ (row&7).
template <int EPI, int AFP32>
__global__ __launch_bounds__(256, 2) void gemm_k(
    const void* __restrict__ Av, const __bf16* __restrict__ WT,
    const float* __restrict__ bias, __bf16* __restrict__ OUT,
    const __bf16* __restrict__ XRES, const int* __restrict__ idx,
    const __bf16* __restrict__ zpage, int M, int K, int Kreal, int nwg) {
  __shared__ __align__(16) __bf16 sm[2][2][128 * 64];
  const int t = threadIdx.x;
  const int w = t >> 6, lane = t & 63;
  // bijective XCD swizzle; logical wg = m*3 + n so A-tile sharers are XCD-local
  int orig = blockIdx.x;
  int q = nwg >> 3, r = nwg & 7, xcd = orig & 7, lid = orig >> 3;
  int wg = (xcd < r ? xcd * (q + 1) : r * (q + 1) + (xcd - r) * q) + lid;
  const int m0 = (wg / 3) * 128;
  const int n0 = (wg % 3) * 128;
  const int fr = lane & 15, fq = lane >> 4;
  const int wr = (w >> 1) * 64, wc = (w & 1) * 64;

  const __bf16* bptr[4];
  const __bf16* aptr[4];
  int aadv[4];
#pragma unroll
  for (int j = 0; j < 4; ++j) {
    int rloc = w * 32 + j * 8 + (lane >> 3);
    int cch = (lane & 7) ^ (rloc & 7);
    bptr[j] = WT + (size_t)(n0 + rloc) * K + cch * 8;
    if constexpr (!AFP32) {
      int gm = m0 + rloc;
      int ar = idx ? idx[gm] : gm;
      if (ar >= 0) { aptr[j] = (const __bf16*)Av + (size_t)ar * K + cch * 8; aadv[j] = 64; }
      else { aptr[j] = zpage; aadv[j] = 0; }
    }
  }
  const float* Af = (const float*)Av;
  const int NT = K >> 6;

  f32x4 acc[4][4];
#pragma unroll
  for (int a = 0; a < 4; ++a)
#pragma unroll
    for (int b = 0; b < 4; ++b)
#pragma unroll
      for (int j = 0; j < 4; ++j) acc[a][b][j] = 0.f;

  auto stage = [&](int buf, int k0) {
    __bf16* As = sm[buf][0];
    __bf16* Bs = sm[buf][1];
    if constexpr (AFP32) {
#pragma unroll
      for (int p = 0; p < 4; ++p) {
        int rr = p * 32 + (t >> 3);
        int cc = t & 7;
        int kb = k0 + cc * 8;
        const float* ap = Af + (size_t)(m0 + rr) * Kreal + kb;
        float vv[8];
        if (kb + 8 <= Kreal) {
          f4 v0 = ld4(ap), v1 = ld4(ap + 4);
#pragma unroll
          for (int e = 0; e < 4; ++e) { vv[e] = v0[e]; vv[4 + e] = v1[e]; }
        } else {
#pragma unroll
          for (int e = 0; e < 8; ++e) vv[e] = (kb + e < Kreal) ? ap[e] : 0.f;
        }
        bf16x8 h;
#pragma unroll
        for (int e = 0; e < 8; ++e) h[e] = (__bf16)vv[e];
        *reinterpret_cast<bf16x8*>(&As[rr * 64 + (((cc ^ (rr & 7)) << 3))]) = h;
      }
    } else {
#pragma unroll
      for (int j = 0; j < 4; ++j) {
        gl_lds16(aptr[j], &As[(w * 32 + j * 8) * 64]);
        aptr[j] += aadv[j];
      }
    }
#pragma unroll
    for (int j = 0; j < 4; ++j) {
      gl_lds16(bptr[j], &Bs[(w * 32 + j * 8) * 64]);
      bptr[j] += 64;
    }
  };

  auto compute = [&](int buf) {
    const __bf16* As = sm[buf][0];
    const __bf16* Bs = sm[buf][1];
#pragma unroll
    for (int kk2 = 0; kk2 < 2; ++kk2) {
      bf16x8 af[4], bv[4];
#pragma unroll
      for (int mi = 0; mi < 4; ++mi) {
        int rr = wr + mi * 16 + fr;
        af[mi] = *reinterpret_cast<const bf16x8*>(
            &As[rr * 64 + (((fq + kk2 * 4) ^ (rr & 7)) << 3)]);
      }
#pragma unroll
      for (int ni = 0; ni < 4; ++ni) {
        int rr = wc + ni * 16 + fr;
        bv[ni] = *reinterpret_cast<const bf16x8*>(
            &Bs[rr * 64 + (((fq + kk2 * 4) ^ (rr & 7)) << 3)]);
      }
#pragma unroll
      for (int mi = 0; mi < 4; ++mi)
#pragma unroll
        for (int ni = 0; ni < 4; ++ni)
          acc[mi][ni] = __builtin_amdgcn_mfma_f32_16x16x32_bf16(af[mi], bv[ni],
                                                                acc[mi][ni], 0, 0, 0);
    }
  };

  stage(0, 0);
  __syncthreads();
  int cur = 0;
  for (int tt = 0; tt < NT; ++tt) {
    if (tt + 1 < NT) stage(cur ^ 1, (tt + 1) << 6);
    compute(cur);
    __syncthreads();
    cur ^= 1;
  }

#pragma unroll
  for (int mi = 0; mi < 4; ++mi)
#pragma unroll
    for (int ni = 0; ni < 4; ++ni) {
      int col = n0 + wc + ni * 16 + fr;
      float bvv = bias[col];
#pragma unroll
      for (int j = 0; j < 4; ++j) {
        int row = m0 + wr + mi * 16 + fq * 4 + j;
        size_t o = (size_t)row * DD + col;
        float v = acc[mi][ni][j] + bvv;
        if constexpr (EPI == 0) {
          OUT[o] = (__bf16)v;
        } else if constexpr (EPI == 1) {
          OUT[o] = (__bf16)fmaxf(v, 0.f);
        } else if constexpr (EPI == 2) {
          OUT[o] = (__bf16)((float)OUT[o] + v);
        } else {
          float gl = (float)OUT[o];
          float g = 1.f / (1.f + expf(-gl));
          OUT[o] = (__bf16)((float)XRES[o] + g * v);
        }
      }
    }
}

// ---------------- LayerNorm: 16 lanes per row, 16 rows/block ----------------
template <int RELU>
__global__ __launch_bounds__(256) void ln_k(const __bf16* __restrict__ x,
                                            const float* __restrict__ g,
                                            const float* __restrict__ b,
                                            __bf16* __restrict__ out) {
  int w = threadIdx.x >> 6, lane = threadIdx.x & 63;
  int s = lane & 15, qq = lane >> 4;
  int row = blockIdx.x * 16 + w * 4 + qq;
  size_t base = (size_t)row * DD;
  float v[24];
#pragma unroll
  for (int i = 0; i < 3; ++i) {
    bf16x8 h = ld8h(x + base + (s + 16 * i) * 8);
#pragma unroll
    for (int e = 0; e < 8; ++e) v[i * 8 + e] = (float)h[e];
  }
  float sm = 0.f;
#pragma unroll
  for (int i = 0; i < 24; ++i) sm += v[i];
  sm = gred16(sm);
  float mean = sm * (1.f / 384.f);
  float qs = 0.f;
#pragma unroll
  for (int i = 0; i < 24; ++i) { float d = v[i] - mean; qs += d * d; }
  qs = gred16(qs);
  float rs = rsqrtf(qs * (1.f / 384.f) + 1e-3f);
#pragma unroll
  for (int i = 0; i < 3; ++i) {
    int col = (s + 16 * i) * 8;
    f4 g0 = ld4(g + col), g1 = ld4(g + col + 4);
    f4 b0 = ld4(b + col), b1 = ld4(b + col + 4);
    bf16x8 o;
#pragma unroll
    for (int e = 0; e < 4; ++e) {
      float y0 = (v[i * 8 + e] - mean) * rs * g0[e] + b0[e];
      float y1 = (v[i * 8 + 4 + e] - mean) * rs * g1[e] + b1[e];
      if (RELU) { y0 = fmaxf(y0, 0.f); y1 = fmaxf(y1, 0.f); }
      o[e] = (__bf16)y0; o[4 + e] = (__bf16)y1;
    }
    st8h(out + base + col, o);
  }
}

// LN(net_fp32 + inp_fp32 + h_bf16)
__global__ __launch_bounds__(256) void ln3_k(const float* __restrict__ x1,
                                             const float* __restrict__ x2,
                                             const __bf16* __restrict__ x3,
                                             const float* __restrict__ g,
                                             const float* __restrict__ b,
                                             __bf16* __restrict__ out) {
  int w = threadIdx.x >> 6, lane = threadIdx.x & 63;
  int s = lane & 15, qq = lane >> 4;
  int row = blockIdx.x * 16 + w * 4 + qq;
  size_t base = (size_t)row * DD;
  float v[24];
#pragma unroll
  for (int i = 0; i < 3; ++i) {
    int col = (s + 16 * i) * 8;
    f4 a0 = ld4(x1 + base + col), a1 = ld4(x1 + base + col + 4);
    f4 c0 = ld4(x2 + base + col), c1 = ld4(x2 + base + col + 4);
    bf16x8 h = ld8h(x3 + base + col);
#pragma unroll
    for (int e = 0; e < 4; ++e) {
      v[i * 8 + e] = a0[e] + c0[e] + (float)h[e];
      v[i * 8 + 4 + e] = a1[e] + c1[e] + (float)h[4 + e];
    }
  }
  float sm = 0.f;
#pragma unroll
  for (int i = 0; i < 24; ++i) sm += v[i];
  sm = gred16(sm);
  float mean = sm * (1.f / 384.f);
  float qs = 0.f;
#pragma unroll
  for (int i = 0; i < 24; ++i) { float d = v[i] - mean; qs += d * d; }
  qs = gred16(qs);
  float rs = rsqrtf(qs * (1.f / 384.f) + 1e-3f);
#pragma unroll
  for (int i = 0; i < 3; ++i) {
    int col = (s + 16 * i) * 8;
    f4 g0 = ld4(g + col), g1 = ld4(g + col + 4);
    f4 b0 = ld4(b + col), b1 = ld4(b + col + 4);
    bf16x8 o;
#pragma unroll
    for (int e = 0; e < 4; ++e) {
      o[e] = (__bf16)((v[i * 8 + e] - mean) * rs * g0[e] + b0[e]);
      o[4 + e] = (__bf16)((v[i * 8 + 4 + e] - mean) * rs * g1[e] + b1[e]);
    }
    st8h(out + base + col, o);
  }
}

// ---------------- segment softmax ----------------
__device__ inline unsigned fenc(float f) {
  unsigned u = __float_as_uint(f);
  return (u & 0x80000000u) ? ~u : (u | 0x80000000u);
}
__device__ inline float fdec(unsigned u) {
  unsigned b = (u & 0x80000000u) ? (u ^ 0x80000000u) : ~u;
  return __uint_as_float(b);
}

__global__ __launch_bounds__(256) void segmax_k(const __bf16* __restrict__ L,
                                                const int* __restrict__ gid,
                                                unsigned* __restrict__ gmax) {
  int i = blockIdx.x * 256 + threadIdx.x;
  int row = i / 48, c = (i - row * 48) * 8;
  int g = gid[row];
  bf16x8 v = ld8h(L + (size_t)row * DD + c);
  unsigned* gp = gmax + (size_t)g * DD + c;
#pragma unroll
  for (int e = 0; e < 8; ++e) atomicMax(gp + e, fenc((float)v[e]));
}

__global__ __launch_bounds__(256) void segexp_k(__bf16* __restrict__ L,
                                                const int* __restrict__ gid,
                                                const unsigned* __restrict__ gmax,
                                                float* __restrict__ den) {
  int i = blockIdx.x * 256 + threadIdx.x;
  int row = i / 48, c = (i - row * 48) * 8;
  int g = gid[row];
  size_t lo = (size_t)row * DD + c;
  size_t go = (size_t)g * DD + c;
  bf16x8 v = ld8h(L + lo);
  bf16x8 o;
  float es[8];
#pragma unroll
  for (int e = 0; e < 8; ++e) {
    es[e] = expf((float)v[e] - fdec(gmax[go + e]));
    o[e] = (__bf16)es[e];
  }
  st8h(L + lo, o);
#pragma unroll
  for (int e = 0; e < 8; ++e) atomicAdd(&den[go + e], es[e]);
}

__global__ __launch_bounds__(256) void segwsum_k(const __bf16* __restrict__ E,
                                                 const __bf16* __restrict__ Ft,
                                                 const int* __restrict__ gid,
                                                 const float* __restrict__ den,
                                                 float* __restrict__ yb) {
  int i = blockIdx.x * 256 + threadIdx.x;
  int row = i / 48, c = (i - row * 48) * 8;
  int g = gid[row];
  size_t lo = (size_t)row * DD + c;
  size_t go = (size_t)g * DD + c;
  bf16x8 eV = ld8h(E + lo);
  bf16x8 fV = ld8h(Ft + lo);
#pragma unroll
  for (int e = 0; e < 8; ++e) {
    float wv = (float)eV[e] / (den[go + e] + 1e-12f);
    atomicAdd(&yb[go + e], (float)fV[e] * wv);
  }
}

__global__ __launch_bounds__(256) void addgather_k(__bf16* __restrict__ X,
                                                   const __bf16* __restrict__ z,
                                                   const int* __restrict__ gid) {
  int i = blockIdx.x * 256 + threadIdx.x;
  int row = i / 48, c = (i - row * 48) * 8;
  int g = gid[row];
  size_t lo = (size_t)row * DD + c;
  bf16x8 a = ld8h(X + lo);
  bf16x8 zz = ld8h(z + (size_t)g * DD + c);
  bf16x8 o;
#pragma unroll
  for (int e = 0; e < 8; ++e) o[e] = (__bf16)((float)a[e] + (float)zz[e]);
  st8h(X + lo, o);
}

// ---------------- final: net fp32 out + d/w heads ----------------
__global__ __launch_bounds__(256) void final_k(const __bf16* __restrict__ net,
                                               const float* __restrict__ dw,
                                               const float* __restrict__ db,
                                               const float* __restrict__ ww,
                                               const float* __restrict__ wb,
                                               float* __restrict__ out) {
  int w = threadIdx.x >> 6, lane = threadIdx.x & 63;
  int s = lane & 15, qq = lane >> 4;
  int row = blockIdx.x * 16 + w * 4 + qq;
  size_t base = (size_t)row * DD;
  float d0 = 0, d1 = 0, w0 = 0, w1 = 0;
#pragma unroll
  for (int i = 0; i < 3; ++i) {
    int col = (s + 16 * i) * 8;
    bf16x8 h = ld8h(net + base + col);
    f4 o0, o1;
#pragma unroll
    for (int e = 0; e < 4; ++e) {
      float x0 = (float)h[e], x1 = (float)h[4 + e];
      o0[e] = x0; o1[e] = x1;
      float r0 = fmaxf(x0, 0.f), r1 = fmaxf(x1, 0.f);
      int c0 = col + e, c1 = col + 4 + e;
      d0 += r0 * dw[2 * c0] + r1 * dw[2 * c1];
      d1 += r0 * dw[2 * c0 + 1] + r1 * dw[2 * c1 + 1];
      w0 += r0 * ww[2 * c0] + r1 * ww[2 * c1];
      w1 += r0 * ww[2 * c0 + 1] + r1 * ww[2 * c1 + 1];
    }
    st4(out + base + col, o0);
    st4(out + base + col + 4, o1);
  }
  d0 = gred16(d0); d1 = gred16(d1); w0 = gred16(w0); w1 = gred16(w1);
  if (s == 0) {
    float* outd = out + (size_t)NR * DD;
    float* outw = outd + (size_t)NR * 2;
    outd[2 * row] = d0 + db[0];
    outd[2 * row + 1] = d1 + db[1];
    outw[2 * row] = 1.f / (1.f + expf(-(w0 + wb[0])));
    outw[2 * row + 1] = 1.f / (1.f + expf(-(w1 + wb[1])));
  }
}

extern "C" void kernel_launch(void* const* d_in, const int* in_sizes, int n_in,
                              void* d_out, int out_size, void* d_ws, size_t ws_size,
                              hipStream_t stream) {
  const float* in_net = (const float*)d_in[0];
  const float* in_inp = (const float*)d_in[1];
  const float* in_corr = (const float*)d_in[2];
  const int* nix = (const int*)d_in[3];
  const int* njx = (const int*)d_in[4];
  const int* ukk = (const int*)d_in[5];
  const int* ujk = (const int*)d_in[6];
  auto F = [&](int i) { return (const float*)d_in[i]; };

  constexpr size_t SZ_ACT = (size_t)NR * DD * 2;       // 25,165,824 bf16 act
  constexpr size_t SZ_SEG4 = (size_t)4096 * DD * 4;    // 6,291,456
  char* ws = (char*)d_ws;
  __bf16* T1b = (__bf16*)(ws);
  __bf16* T2b = (__bf16*)(ws + SZ_ACT);
  __bf16* Fb = (__bf16*)(ws + 2 * SZ_ACT);
  __bf16* zb = (__bf16*)(ws + 3 * SZ_ACT);                       // 3 MB
  unsigned* gmax = (unsigned*)(ws + 3 * SZ_ACT + 4 * 1024 * 1024);
  float* den = (float*)((char*)gmax + SZ_SEG4);
  float* yb = (float*)((char*)den + SZ_SEG4);
  __bf16* wt_all = (__bf16*)((char*)yb + SZ_SEG4);               // 18 * DD*DD
  __bf16* wt_corr1 = wt_all + (size_t)18 * DD * DD;              // DD * CDMP
  __bf16* zpage = wt_corr1 + (size_t)DD * CDMP;                  // 256 B zeros

  // weight transpose order in wt_all:
  // 0 c1a(17) 1 c1b(19) 2 c2a(21) 3 c2b(23) 4 kkf(25) 5 kkg(27) 6 kkh(29)
  // 7 ijf(31) 8 ijg(33) 9 ijh(35) 10 g1g(39) 11 g1r1(41) 12 g1r2(43)
  // 13 g2g(47) 14 g2r1(49) 15 g2r2(51) 16 corr2(9) 17 corr3(13)
  const int widx[18] = {17, 19, 21, 23, 25, 27, 29, 31, 33, 35, 39, 41, 43, 47, 49, 51, 9, 13};
  WPtrs P;
  for (int i = 0; i < 18; ++i) P.w[i] = F(widx[i]);
  auto WTp = [&](int i) { return wt_all + (size_t)i * DD * DD; };

  hipMemsetAsync(zpage, 0, 256, stream);
  trans_all_k<<<dim3(576, 18), 256, 0, stream>>>(P, wt_all);
  trans_corr_k<<<1344, 256, 0, stream>>>(in_corr == nullptr ? F(7) : F(7), wt_corr1);

  auto GEMM = [&](int epi, int afp32, const void* A, const __bf16* WT, const float* bias,
                  __bf16* OUT, const __bf16* XRES, const int* idx, int M, int Kp, int Kr) {
    int nwg = (M / 128) * 3;
    dim3 g(nwg), b(256);
    if (afp32) {
      if (epi == 1)
        gemm_k<1, 1><<<g, b, 0, stream>>>(A, WT, bias, OUT, XRES, idx, zpage, M, Kp, Kr, nwg);
      else
        gemm_k<0, 1><<<g, b, 0, stream>>>(A, WT, bias, OUT, XRES, idx, zpage, M, Kp, Kr, nwg);
    } else {
      switch (epi) {
        case 0: gemm_k<0, 0><<<g, b, 0, stream>>>(A, WT, bias, OUT, XRES, idx, zpage, M, Kp, Kr, nwg); break;
        case 1: gemm_k<1, 0><<<g, b, 0, stream>>>(A, WT, bias, OUT, XRES, idx, zpage, M, Kp, Kr, nwg); break;
        case 2: gemm_k<2, 0><<<g, b, 0, stream>>>(A, WT, bias, OUT, XRES, idx, zpage, M, Kp, Kr, nwg); break;
        default: gemm_k<3, 0><<<g, b, 0, stream>>>(A, WT, bias, OUT, XRES, idx, zpage, M, Kp, Kr, nwg); break;
      }
    }
  };

  const int LNG = NR / 16;
  const int SEGB = NR * 48 / 256;

  // corr encoder
  GEMM(1, 1, in_corr, wt_corr1, F(8), T1b, nullptr, nullptr, NR, CDMP, CDM);
  GEMM(0, 0, T1b, WTp(16), F(10), T2b, nullptr, nullptr, NR, DD, DD);
  ln_k<1><<<LNG, 256, 0, stream>>>(T2b, F(11), F(12), T1b);
  GEMM(0, 0, T1b, WTp(17), F(14), T2b, nullptr, nullptr, NR, DD, DD);
  // net2 = LN(net + inp + h)
  ln3_k<<<LNG, 256, 0, stream>>>(in_net, in_inp, T2b, F(15), F(16), T1b);
  // c1
  GEMM(1, 0, T1b, WTp(0), F(18), T2b, nullptr, nix, NR, DD, DD);
  GEMM(2, 0, T2b, WTp(1), F(20), T1b, nullptr, nullptr, NR, DD, DD);  // net3
  // c2
  GEMM(1, 0, T1b, WTp(2), F(22), T2b, nullptr, njx, NR, DD, DD);
  GEMM(2, 0, T2b, WTp(3), F(24), T1b, nullptr, nullptr, NR, DD, DD);  // net4
  // kk soft-agg (G=4096)
  GEMM(0, 0, T1b, WTp(5), F(28), T2b, nullptr, nullptr, NR, DD, DD);  // logits
  GEMM(0, 0, T1b, WTp(4), F(26), Fb, nullptr, nullptr, NR, DD, DD);   // feats
  hipMemsetAsync(gmax, 0, (size_t)4096 * DD * 4, stream);
  hipMemsetAsync(den, 0, (size_t)4096 * DD * 4, stream);
  hipMemsetAsync(yb, 0, (size_t)4096 * DD * 4, stream);
  segmax_k<<<SEGB, 256, 0, stream>>>(T2b, ukk, gmax);
  segexp_k<<<SEGB, 256, 0, stream>>>(T2b, ukk, gmax, den);
  segwsum_k<<<SEGB, 256, 0, stream>>>(T2b, Fb, ukk, den, yb);
  GEMM(0, 1, yb, WTp(6), F(30), zb, nullptr, nullptr, 4096, DD, DD);
  addgather_k<<<SEGB, 256, 0, stream>>>(T1b, zb, ukk);                // net5
  // ij soft-agg (G=512)
  GEMM(0, 0, T1b, WTp(8), F(34), T2b, nullptr, nullptr, NR, DD, DD);
  GEMM(0, 0, T1b, WTp(7), F(32), Fb, nullptr, nullptr, NR, DD, DD);
  hipMemsetAsync(gmax, 0, (size_t)512 * DD * 4, stream);
  hipMemsetAsync(den, 0, (size_t)512 * DD * 4, stream);
  hipMemsetAsync(yb, 0, (size_t)512 * DD * 4, stream);
  segmax_k<<<SEGB, 256, 0, stream>>>(T2b, ujk, gmax);
  segexp_k<<<SEGB, 256, 0, stream>>>(T2b, ujk, gmax, den);
  segwsum_k<<<SEGB, 256, 0, stream>>>(T2b, Fb, ujk, den, yb);
  GEMM(0, 1, yb, WTp(9), F(36), zb, nullptr, nullptr, 512, DD, DD);
  addgather_k<<<SEGB, 256, 0, stream>>>(T1b, zb, ujk);                // net6
  // gated residual 1
  ln_k<0><<<LNG, 256, 0, stream>>>(T1b, F(37), F(38), T2b);           // x = LN(net6)
  GEMM(0, 0, T2b, WTp(10), F(40), Fb, nullptr, nullptr, NR, DD, DD);  // gate logits
  GEMM(1, 0, T2b, WTp(11), F(42), T1b, nullptr, nullptr, NR, DD, DD); // relu hidden
  GEMM(3, 0, T1b, WTp(12), F(44), Fb, T2b, nullptr, NR, DD, DD);      // Fb = net7
  // gated residual 2
  ln_k<0><<<LNG, 256, 0, stream>>>(Fb, F(45), F(46), T1b);            // x = LN(net7)
  GEMM(0, 0, T1b, WTp(13), F(48), T2b, nullptr, nullptr, NR, DD, DD);
  GEMM(1, 0, T1b, WTp(14), F(50), Fb, nullptr, nullptr, NR, DD, DD);
  GEMM(3, 0, Fb, WTp(15), F(52), T2b, T1b, nullptr, NR, DD, DD);      // T2b = net9
  // outputs
  final_k<<<LNG, 256, 0, stream>>>(T2b, F(53), F(54), F(55), F(56), (float*)d_out);
}

// Round 4
// 742.441 us; speedup vs baseline: 3.4535x; 3.4535x over previous
//
#include <hip/hip_runtime.h>
#include <hip/hip_bf16.h>
#include <math.h>

#define NR 32768
#define DD 384
#define CDM 882
#define CDMP 896

typedef float f4 __attribute__((ext_vector_type(4)));
typedef float f32x4 __attribute__((ext_vector_type(4)));
typedef __bf16 bf16x8 __attribute__((ext_vector_type(8)));
typedef __bf16 bf16x4 __attribute__((ext_vector_type(4)));

__device__ inline f4 ld4(const float* p) { f4 v; __builtin_memcpy(&v, p, 16); return v; }
__device__ inline void st4(float* p, f4 v) { __builtin_memcpy(p, &v, 16); }
__device__ inline bf16x8 ld8h(const __bf16* p) { bf16x8 v; __builtin_memcpy(&v, p, 16); return v; }
__device__ inline void st8h(__bf16* p, bf16x8 v) { __builtin_memcpy(p, &v, 16); }

__device__ inline void gl_lds16(const void* g, void* l) {
  __builtin_amdgcn_global_load_lds(
      (const __attribute__((address_space(1))) void*)g,
      (__attribute__((address_space(3))) void*)l, 16, 0, 0);
}

__device__ inline float gred16(float v) {
#pragma unroll
  for (int o = 1; o < 16; o <<= 1) v += __shfl_xor(v, o, 64);
  return v;
}

// ---------------- weight transposes (fused) ----------------
struct WPtrs { const float* w[18]; };

__global__ __launch_bounds__(256) void trans_all_k(WPtrs P, __bf16* __restrict__ dst) {
  int wi = blockIdx.y;
  const float* W = P.w[wi];
  __bf16* WT = dst + (size_t)wi * DD * DD;
  int i = blockIdx.x * 256 + threadIdx.x;
  if (i >= DD * DD) return;
  int n = i / DD, k = i - n * DD;
  WT[i] = (__bf16)W[(size_t)k * DD + n];
}

__global__ __launch_bounds__(256) void trans_corr_k(const float* __restrict__ W,
                                                    __bf16* __restrict__ WT) {
  int i = blockIdx.x * 256 + threadIdx.x;
  if (i >= DD * CDMP) return;
  int n = i / CDMP, k = i - n * CDMP;
  WT[i] = (k < CDM) ? (__bf16)W[(size_t)k * DD + n] : (__bf16)0.f;
}

// ---------------- MFMA GEMM: OUT[M,384] = epi(A[M,K] @ W) ----------------
// EPI: 0 store, 1 relu, 2 OUT += v (in-place), 3 OUT = XRES + sigmoid(OUT)*v
// AFP32: A is fp32 (reg-stage + convert); else bf16 via global_load_lds.
// LDS tiles [128][64] bf16, chunk(16B)-XOR swizzle: pos chunk = c ^ (row&7).
template <int EPI, int AFP32>
__global__ __launch_bounds__(256, 2) void gemm_k(
    const void* __restrict__ Av, const __bf16* __restrict__ WT,
    const float* __restrict__ bias, __bf16* __restrict__ OUT,
    const __bf16* __restrict__ XRES, const int* __restrict__ idx,
    const __bf16* __restrict__ zpage, int M, int K, int Kreal, int nwg) {
  __shared__ __align__(16) __bf16 sm[2][2][128 * 64];
  const int t = threadIdx.x;
  const int w = t >> 6, lane = t & 63;
  // bijective XCD swizzle; logical wg = m*3 + n so A-tile sharers are XCD-local
  int orig = blockIdx.x;
  int q = nwg >> 3, r = nwg & 7, xcd = orig & 7, lid = orig >> 3;
  int wg = (xcd < r ? xcd * (q + 1) : r * (q + 1) + (xcd - r) * q) + lid;
  const int m0 = (wg / 3) * 128;
  const int n0 = (wg % 3) * 128;
  const int fr = lane & 15, fq = lane >> 4;
  const int wr = (w >> 1) * 64, wc = (w & 1) * 64;

  const __bf16* bptr[4];
  const __bf16* aptr[4];
  int aadv[4];
#pragma unroll
  for (int j = 0; j < 4; ++j) {
    int rloc = w * 32 + j * 8 + (lane >> 3);
    int cch = (lane & 7) ^ (rloc & 7);
    bptr[j] = WT + (size_t)(n0 + rloc) * K + cch * 8;
    if constexpr (!AFP32) {
      int gm = m0 + rloc;
      int ar = idx ? idx[gm] : gm;
      if (ar >= 0) { aptr[j] = (const __bf16*)Av + (size_t)ar * K + cch * 8; aadv[j] = 64; }
      else { aptr[j] = zpage; aadv[j] = 0; }
    }
  }
  const float* Af = (const float*)Av;
  const int NT = K >> 6;

  f32x4 acc[4][4];
#pragma unroll
  for (int a = 0; a < 4; ++a)
#pragma unroll
    for (int b = 0; b < 4; ++b)
#pragma unroll
      for (int j = 0; j < 4; ++j) acc[a][b][j] = 0.f;

  auto stage = [&](int buf, int k0) {
    __bf16* As = sm[buf][0];
    __bf16* Bs = sm[buf][1];
    if constexpr (AFP32) {
#pragma unroll
      for (int p = 0; p < 4; ++p) {
        int rr = p * 32 + (t >> 3);
        int cc = t & 7;
        int kb = k0 + cc * 8;
        const float* ap = Af + (size_t)(m0 + rr) * Kreal + kb;
        float vv[8];
        if (kb + 8 <= Kreal) {
          f4 v0 = ld4(ap), v1 = ld4(ap + 4);
#pragma unroll
          for (int e = 0; e < 4; ++e) { vv[e] = v0[e]; vv[4 + e] = v1[e]; }
        } else {
#pragma unroll
          for (int e = 0; e < 8; ++e) vv[e] = (kb + e < Kreal) ? ap[e] : 0.f;
        }
        bf16x8 h;
#pragma unroll
        for (int e = 0; e < 8; ++e) h[e] = (__bf16)vv[e];
        *reinterpret_cast<bf16x8*>(&As[rr * 64 + (((cc ^ (rr & 7)) << 3))]) = h;
      }
    } else {
#pragma unroll
      for (int j = 0; j < 4; ++j) {
        gl_lds16(aptr[j], &As[(w * 32 + j * 8) * 64]);
        aptr[j] += aadv[j];
      }
    }
#pragma unroll
    for (int j = 0; j < 4; ++j) {
      gl_lds16(bptr[j], &Bs[(w * 32 + j * 8) * 64]);
      bptr[j] += 64;
    }
  };

  auto compute = [&](int buf) {
    const __bf16* As = sm[buf][0];
    const __bf16* Bs = sm[buf][1];
#pragma unroll
    for (int kk2 = 0; kk2 < 2; ++kk2) {
      bf16x8 af[4], bv[4];
#pragma unroll
      for (int mi = 0; mi < 4; ++mi) {
        int rr = wr + mi * 16 + fr;
        af[mi] = *reinterpret_cast<const bf16x8*>(
            &As[rr * 64 + (((fq + kk2 * 4) ^ (rr & 7)) << 3)]);
      }
#pragma unroll
      for (int ni = 0; ni < 4; ++ni) {
        int rr = wc + ni * 16 + fr;
        bv[ni] = *reinterpret_cast<const bf16x8*>(
            &Bs[rr * 64 + (((fq + kk2 * 4) ^ (rr & 7)) << 3)]);
      }
#pragma unroll
      for (int mi = 0; mi < 4; ++mi)
#pragma unroll
        for (int ni = 0; ni < 4; ++ni)
          acc[mi][ni] = __builtin_amdgcn_mfma_f32_16x16x32_bf16(af[mi], bv[ni],
                                                                acc[mi][ni], 0, 0, 0);
    }
  };

  stage(0, 0);
  __syncthreads();
  int cur = 0;
  for (int tt = 0; tt < NT; ++tt) {
    if (tt + 1 < NT) stage(cur ^ 1, (tt + 1) << 6);
    compute(cur);
    __syncthreads();
    cur ^= 1;
  }

#pragma unroll
  for (int mi = 0; mi < 4; ++mi)
#pragma unroll
    for (int ni = 0; ni < 4; ++ni) {
      int col = n0 + wc + ni * 16 + fr;
      float bvv = bias[col];
#pragma unroll
      for (int j = 0; j < 4; ++j) {
        int row = m0 + wr + mi * 16 + fq * 4 + j;
        size_t o = (size_t)row * DD + col;
        float v = acc[mi][ni][j] + bvv;
        if constexpr (EPI == 0) {
          OUT[o] = (__bf16)v;
        } else if constexpr (EPI == 1) {
          OUT[o] = (__bf16)fmaxf(v, 0.f);
        } else if constexpr (EPI == 2) {
          OUT[o] = (__bf16)((float)OUT[o] + v);
        } else {
          float gl = (float)OUT[o];
          float g = 1.f / (1.f + expf(-gl));
          OUT[o] = (__bf16)((float)XRES[o] + g * v);
        }
      }
    }
}

// ---------------- LayerNorm: 16 lanes per row, 16 rows/block ----------------
template <int RELU>
__global__ __launch_bounds__(256) void ln_k(const __bf16* __restrict__ x,
                                            const float* __restrict__ g,
                                            const float* __restrict__ b,
                                            __bf16* __restrict__ out) {
  int w = threadIdx.x >> 6, lane = threadIdx.x & 63;
  int s = lane & 15, qq = lane >> 4;
  int row = blockIdx.x * 16 + w * 4 + qq;
  size_t base = (size_t)row * DD;
  float v[24];
#pragma unroll
  for (int i = 0; i < 3; ++i) {
    bf16x8 h = ld8h(x + base + (s + 16 * i) * 8);
#pragma unroll
    for (int e = 0; e < 8; ++e) v[i * 8 + e] = (float)h[e];
  }
  float sm = 0.f;
#pragma unroll
  for (int i = 0; i < 24; ++i) sm += v[i];
  sm = gred16(sm);
  float mean = sm * (1.f / 384.f);
  float qs = 0.f;
#pragma unroll
  for (int i = 0; i < 24; ++i) { float d = v[i] - mean; qs += d * d; }
  qs = gred16(qs);
  float rs = rsqrtf(qs * (1.f / 384.f) + 1e-3f);
#pragma unroll
  for (int i = 0; i < 3; ++i) {
    int col = (s + 16 * i) * 8;
    f4 g0 = ld4(g + col), g1 = ld4(g + col + 4);
    f4 b0 = ld4(b + col), b1 = ld4(b + col + 4);
    bf16x8 o;
#pragma unroll
    for (int e = 0; e < 4; ++e) {
      float y0 = (v[i * 8 + e] - mean) * rs * g0[e] + b0[e];
      float y1 = (v[i * 8 + 4 + e] - mean) * rs * g1[e] + b1[e];
      if (RELU) { y0 = fmaxf(y0, 0.f); y1 = fmaxf(y1, 0.f); }
      o[e] = (__bf16)y0; o[4 + e] = (__bf16)y1;
    }
    st8h(out + base + col, o);
  }
}

// LN(net_fp32 + inp_fp32 + h_bf16)
__global__ __launch_bounds__(256) void ln3_k(const float* __restrict__ x1,
                                             const float* __restrict__ x2,
                                             const __bf16* __restrict__ x3,
                                             const float* __restrict__ g,
                                             const float* __restrict__ b,
                                             __bf16* __restrict__ out) {
  int w = threadIdx.x >> 6, lane = threadIdx.x & 63;
  int s = lane & 15, qq = lane >> 4;
  int row = blockIdx.x * 16 + w * 4 + qq;
  size_t base = (size_t)row * DD;
  float v[24];
#pragma unroll
  for (int i = 0; i < 3; ++i) {
    int col = (s + 16 * i) * 8;
    f4 a0 = ld4(x1 + base + col), a1 = ld4(x1 + base + col + 4);
    f4 c0 = ld4(x2 + base + col), c1 = ld4(x2 + base + col + 4);
    bf16x8 h = ld8h(x3 + base + col);
#pragma unroll
    for (int e = 0; e < 4; ++e) {
      v[i * 8 + e] = a0[e] + c0[e] + (float)h[e];
      v[i * 8 + 4 + e] = a1[e] + c1[e] + (float)h[4 + e];
    }
  }
  float sm = 0.f;
#pragma unroll
  for (int i = 0; i < 24; ++i) sm += v[i];
  sm = gred16(sm);
  float mean = sm * (1.f / 384.f);
  float qs = 0.f;
#pragma unroll
  for (int i = 0; i < 24; ++i) { float d = v[i] - mean; qs += d * d; }
  qs = gred16(qs);
  float rs = rsqrtf(qs * (1.f / 384.f) + 1e-3f);
#pragma unroll
  for (int i = 0; i < 3; ++i) {
    int col = (s + 16 * i) * 8;
    f4 g0 = ld4(g + col), g1 = ld4(g + col + 4);
    f4 b0 = ld4(b + col), b1 = ld4(b + col + 4);
    bf16x8 o;
#pragma unroll
    for (int e = 0; e < 4; ++e) {
      o[e] = (__bf16)((v[i * 8 + e] - mean) * rs * g0[e] + b0[e]);
      o[4 + e] = (__bf16)((v[i * 8 + 4 + e] - mean) * rs * g1[e] + b1[e]);
    }
    st8h(out + base + col, o);
  }
}

// ---------------- segment softmax via counting sort + fused block-per-group ----
__global__ __launch_bounds__(256) void hist_k(const int* __restrict__ gid,
                                              int* __restrict__ cnt, int n) {
  int i = blockIdx.x * 256 + threadIdx.x;
  if (i < n) atomicAdd(&cnt[gid[i]], 1);
}

// exclusive scan of cnt[0..G) -> off[0..G], single block of 256 threads
__global__ __launch_bounds__(256) void scan_k(const int* __restrict__ cnt,
                                              int* __restrict__ off, int G) {
  __shared__ int ls[256];
  int t = threadIdx.x;
  int per = G / 256;
  int base = t * per;
  int s = 0;
  for (int i = 0; i < per; ++i) s += cnt[base + i];
  ls[t] = s;
  __syncthreads();
  for (int o = 1; o < 256; o <<= 1) {
    int v = (t >= o) ? ls[t - o] : 0;
    __syncthreads();
    ls[t] += v;
    __syncthreads();
  }
  int run = (t == 0) ? 0 : ls[t - 1];
  for (int i = 0; i < per; ++i) {
    off[base + i] = run;
    run += cnt[base + i];
  }
  if (t == 255) off[G] = run;
}

__global__ __launch_bounds__(256) void scatter_k(const int* __restrict__ gid,
                                                 const int* __restrict__ off,
                                                 int* __restrict__ cur,
                                                 int* __restrict__ rows, int n) {
  int i = blockIdx.x * 256 + threadIdx.x;
  if (i >= n) return;
  int g = gid[i];
  int p = atomicAdd(&cur[g], 1);
  rows[off[g] + p] = i;
}

// one block per group, 384 threads = one per column
// y[g][c] = sum_r F[r][c]*exp(L[r][c]-mx[c]) / (sum_r exp(L[r][c]-mx[c]) + 1e-12)
__global__ __launch_bounds__(384) void segagg_k(const __bf16* __restrict__ L,
                                                const __bf16* __restrict__ Ft,
                                                const int* __restrict__ rows,
                                                const int* __restrict__ off,
                                                float* __restrict__ yb) {
  int g = blockIdx.x;
  int c = threadIdx.x;
  int s = off[g], e = off[g + 1];
  float mx = -3.0e38f;
  for (int p = s; p < e; ++p) {
    int r = rows[p];
    mx = fmaxf(mx, (float)L[(size_t)r * DD + c]);
  }
  float num = 0.f, den = 0.f;
  for (int p = s; p < e; ++p) {
    int r = rows[p];
    float lv = (float)L[(size_t)r * DD + c];
    float fv = (float)Ft[(size_t)r * DD + c];
    float ev = expf(lv - mx);
    den += ev;
    num += fv * ev;
  }
  yb[(size_t)g * DD + c] = num / (den + 1e-12f);
}

__global__ __launch_bounds__(256) void addgather_k(__bf16* __restrict__ X,
                                                   const __bf16* __restrict__ z,
                                                   const int* __restrict__ gid) {
  int i = blockIdx.x * 256 + threadIdx.x;
  int row = i / 48, c = (i - row * 48) * 8;
  int g = gid[row];
  size_t lo = (size_t)row * DD + c;
  bf16x8 a = ld8h(X + lo);
  bf16x8 zz = ld8h(z + (size_t)g * DD + c);
  bf16x8 o;
#pragma unroll
  for (int e = 0; e < 8; ++e) o[e] = (__bf16)((float)a[e] + (float)zz[e]);
  st8h(X + lo, o);
}

// ---------------- final: net fp32 out + d/w heads ----------------
__global__ __launch_bounds__(256) void final_k(const __bf16* __restrict__ net,
                                               const float* __restrict__ dw,
                                               const float* __restrict__ db,
                                               const float* __restrict__ ww,
                                               const float* __restrict__ wb,
                                               float* __restrict__ out) {
  int w = threadIdx.x >> 6, lane = threadIdx.x & 63;
  int s = lane & 15, qq = lane >> 4;
  int row = blockIdx.x * 16 + w * 4 + qq;
  size_t base = (size_t)row * DD;
  float d0 = 0, d1 = 0, w0 = 0, w1 = 0;
#pragma unroll
  for (int i = 0; i < 3; ++i) {
    int col = (s + 16 * i) * 8;
    bf16x8 h = ld8h(net + base + col);
    f4 o0, o1;
#pragma unroll
    for (int e = 0; e < 4; ++e) {
      float x0 = (float)h[e], x1 = (float)h[4 + e];
      o0[e] = x0; o1[e] = x1;
      float r0 = fmaxf(x0, 0.f), r1 = fmaxf(x1, 0.f);
      int c0 = col + e, c1 = col + 4 + e;
      d0 += r0 * dw[2 * c0] + r1 * dw[2 * c1];
      d1 += r0 * dw[2 * c0 + 1] + r1 * dw[2 * c1 + 1];
      w0 += r0 * ww[2 * c0] + r1 * ww[2 * c1];
      w1 += r0 * ww[2 * c0 + 1] + r1 * ww[2 * c1 + 1];
    }
    st4(out + base + col, o0);
    st4(out + base + col + 4, o1);
  }
  d0 = gred16(d0); d1 = gred16(d1); w0 = gred16(w0); w1 = gred16(w1);
  if (s == 0) {
    float* outd = out + (size_t)NR * DD;
    float* outw = outd + (size_t)NR * 2;
    outd[2 * row] = d0 + db[0];
    outd[2 * row + 1] = d1 + db[1];
    outw[2 * row] = 1.f / (1.f + expf(-(w0 + wb[0])));
    outw[2 * row + 1] = 1.f / (1.f + expf(-(w1 + wb[1])));
  }
}

extern "C" void kernel_launch(void* const* d_in, const int* in_sizes, int n_in,
                              void* d_out, int out_size, void* d_ws, size_t ws_size,
                              hipStream_t stream) {
  const float* in_net = (const float*)d_in[0];
  const float* in_inp = (const float*)d_in[1];
  const float* in_corr = (const float*)d_in[2];
  const int* nix = (const int*)d_in[3];
  const int* njx = (const int*)d_in[4];
  const int* ukk = (const int*)d_in[5];
  const int* ujk = (const int*)d_in[6];
  auto F = [&](int i) { return (const float*)d_in[i]; };

  constexpr size_t SZ_ACT = (size_t)NR * DD * 2;  // 24 MB bf16 act
  char* ws = (char*)d_ws;
  __bf16* T1b = (__bf16*)(ws);
  __bf16* T2b = (__bf16*)(ws + SZ_ACT);
  __bf16* Fb = (__bf16*)(ws + 2 * SZ_ACT);
  __bf16* zb = (__bf16*)(ws + 3 * SZ_ACT);                       // 4 MB region
  char* p = ws + 3 * SZ_ACT + 4ull * 1024 * 1024;
  float* yb = (float*)p; p += (size_t)4096 * DD * 4;             // 6 MB
  int* rows = (int*)p; p += (size_t)NR * 4;                      // 128 KB
  int* off = (int*)p; p += 32768;                                // 8192 ints (need 4097)
  int* cnt = (int*)p; p += 16384;                                // 4096 ints
  int* curb = (int*)p; p += 16384;                               // 4096 ints
  __bf16* wt_all = (__bf16*)p; p += (size_t)18 * DD * DD * 2;
  __bf16* wt_corr1 = (__bf16*)p; p += (size_t)DD * CDMP * 2;
  __bf16* zpage = (__bf16*)p;

  const int widx[18] = {17, 19, 21, 23, 25, 27, 29, 31, 33, 35, 39, 41, 43, 47, 49, 51, 9, 13};
  WPtrs P;
  for (int i = 0; i < 18; ++i) P.w[i] = F(widx[i]);
  auto WTp = [&](int i) { return wt_all + (size_t)i * DD * DD; };

  hipMemsetAsync(zpage, 0, 256, stream);
  trans_all_k<<<dim3(576, 18), 256, 0, stream>>>(P, wt_all);
  trans_corr_k<<<1344, 256, 0, stream>>>(F(7), wt_corr1);

  auto GEMM = [&](int epi, int afp32, const void* A, const __bf16* WT, const float* bias,
                  __bf16* OUT, const __bf16* XRES, const int* idx, int M, int Kp, int Kr) {
    int nwg = (M / 128) * 3;
    dim3 g(nwg), b(256);
    if (afp32) {
      if (epi == 1)
        gemm_k<1, 1><<<g, b, 0, stream>>>(A, WT, bias, OUT, XRES, idx, zpage, M, Kp, Kr, nwg);
      else
        gemm_k<0, 1><<<g, b, 0, stream>>>(A, WT, bias, OUT, XRES, idx, zpage, M, Kp, Kr, nwg);
    } else {
      switch (epi) {
        case 0: gemm_k<0, 0><<<g, b, 0, stream>>>(A, WT, bias, OUT, XRES, idx, zpage, M, Kp, Kr, nwg); break;
        case 1: gemm_k<1, 0><<<g, b, 0, stream>>>(A, WT, bias, OUT, XRES, idx, zpage, M, Kp, Kr, nwg); break;
        case 2: gemm_k<2, 0><<<g, b, 0, stream>>>(A, WT, bias, OUT, XRES, idx, zpage, M, Kp, Kr, nwg); break;
        default: gemm_k<3, 0><<<g, b, 0, stream>>>(A, WT, bias, OUT, XRES, idx, zpage, M, Kp, Kr, nwg); break;
      }
    }
  };

  // fused segment softmax-aggregation: build rowlists, then one block/group
  auto SEGAGG = [&](const int* gid, int G, const __bf16* L, const __bf16* Ft) {
    hipMemsetAsync(cnt, 0, (size_t)G * 4, stream);
    hipMemsetAsync(curb, 0, (size_t)G * 4, stream);
    hist_k<<<NR / 256, 256, 0, stream>>>(gid, cnt, NR);
    scan_k<<<1, 256, 0, stream>>>(cnt, off, G);
    scatter_k<<<NR / 256, 256, 0, stream>>>(gid, off, curb, rows, NR);
    segagg_k<<<G, 384, 0, stream>>>(L, Ft, rows, off, yb);
  };

  const int LNG = NR / 16;
  const int SEGB = NR * 48 / 256;

  // corr encoder
  GEMM(1, 1, in_corr, wt_corr1, F(8), T1b, nullptr, nullptr, NR, CDMP, CDM);
  GEMM(0, 0, T1b, WTp(16), F(10), T2b, nullptr, nullptr, NR, DD, DD);
  ln_k<1><<<LNG, 256, 0, stream>>>(T2b, F(11), F(12), T1b);
  GEMM(0, 0, T1b, WTp(17), F(14), T2b, nullptr, nullptr, NR, DD, DD);
  // net2 = LN(net + inp + h)
  ln3_k<<<LNG, 256, 0, stream>>>(in_net, in_inp, T2b, F(15), F(16), T1b);
  // c1
  GEMM(1, 0, T1b, WTp(0), F(18), T2b, nullptr, nix, NR, DD, DD);
  GEMM(2, 0, T2b, WTp(1), F(20), T1b, nullptr, nullptr, NR, DD, DD);  // net3
  // c2
  GEMM(1, 0, T1b, WTp(2), F(22), T2b, nullptr, njx, NR, DD, DD);
  GEMM(2, 0, T2b, WTp(3), F(24), T1b, nullptr, nullptr, NR, DD, DD);  // net4
  // kk soft-agg (G=4096)
  GEMM(0, 0, T1b, WTp(5), F(28), T2b, nullptr, nullptr, NR, DD, DD);  // logits
  GEMM(0, 0, T1b, WTp(4), F(26), Fb, nullptr, nullptr, NR, DD, DD);   // feats
  SEGAGG(ukk, 4096, T2b, Fb);
  GEMM(0, 1, yb, WTp(6), F(30), zb, nullptr, nullptr, 4096, DD, DD);
  addgather_k<<<SEGB, 256, 0, stream>>>(T1b, zb, ukk);                // net5
  // ij soft-agg (G=512)
  GEMM(0, 0, T1b, WTp(8), F(34), T2b, nullptr, nullptr, NR, DD, DD);
  GEMM(0, 0, T1b, WTp(7), F(32), Fb, nullptr, nullptr, NR, DD, DD);
  SEGAGG(ujk, 512, T2b, Fb);
  GEMM(0, 1, yb, WTp(9), F(36), zb, nullptr, nullptr, 512, DD, DD);
  addgather_k<<<SEGB, 256, 0, stream>>>(T1b, zb, ujk);                // net6
  // gated residual 1
  ln_k<0><<<LNG, 256, 0, stream>>>(T1b, F(37), F(38), T2b);           // x = LN(net6)
  GEMM(0, 0, T2b, WTp(10), F(40), Fb, nullptr, nullptr, NR, DD, DD);  // gate logits
  GEMM(1, 0, T2b, WTp(11), F(42), T1b, nullptr, nullptr, NR, DD, DD); // relu hidden
  GEMM(3, 0, T1b, WTp(12), F(44), Fb, T2b, nullptr, NR, DD, DD);      // Fb = net7
  // gated residual 2
  ln_k<0><<<LNG, 256, 0, stream>>>(Fb, F(45), F(46), T1b);            // x = LN(net7)
  GEMM(0, 0, T1b, WTp(13), F(48), T2b, nullptr, nullptr, NR, DD, DD);
  GEMM(1, 0, T1b, WTp(14), F(50), Fb, nullptr, nullptr, NR, DD, DD);
  GEMM(3, 0, Fb, WTp(15), F(52), T2b, T1b, nullptr, NR, DD, DD);      // T2b = net9
  // outputs
  final_k<<<LNG, 256, 0, stream>>>(T2b, F(53), F(54), F(55), F(56), (float*)d_out);
}

// Round 5
// 656.393 us; speedup vs baseline: 3.9062x; 1.1311x over previous
//
#include <hip/hip_runtime.h>
#include <hip/hip_bf16.h>
#include <math.h>

#define NR 32768
#define DD 384
#define CDM 882
#define CDMP 896

typedef float f4 __attribute__((ext_vector_type(4)));
typedef float f32x4 __attribute__((ext_vector_type(4)));
typedef __bf16 bf16x8 __attribute__((ext_vector_type(8)));
typedef __bf16 bf16x4 __attribute__((ext_vector_type(4)));

__device__ inline f4 ld4(const float* p) { f4 v; __builtin_memcpy(&v, p, 16); return v; }
__device__ inline void st4(float* p, f4 v) { __builtin_memcpy(p, &v, 16); }
__device__ inline bf16x8 ld8h(const __bf16* p) { bf16x8 v; __builtin_memcpy(&v, p, 16); return v; }
__device__ inline void st8h(__bf16* p, bf16x8 v) { __builtin_memcpy(p, &v, 16); }

__device__ inline void gl_lds16(const void* g, void* l) {
  __builtin_amdgcn_global_load_lds(
      (const __attribute__((address_space(1))) void*)g,
      (__attribute__((address_space(3))) void*)l, 16, 0, 0);
}

__device__ inline float gred16(float v) {
#pragma unroll
  for (int o = 1; o < 16; o <<= 1) v += __shfl_xor(v, o, 64);
  return v;
}

// ---------------- corr fp32 -> bf16, rows padded 882 -> 896 ----------------
__global__ __launch_bounds__(256) void corr2bf16_k(const float* __restrict__ src,
                                                   __bf16* __restrict__ dst) {
  int i = blockIdx.x * 256 + threadIdx.x;  // one thread = 8 outputs
  int row = i / 112, c8 = (i - row * 112) * 8;
  const float* sp = src + (size_t)row * CDM + c8;
  bf16x8 h;
  if (c8 + 8 <= CDM) {
#pragma unroll
    for (int e = 0; e < 8; ++e) h[e] = (__bf16)sp[e];
  } else {
#pragma unroll
    for (int e = 0; e < 8; ++e) h[e] = (c8 + e < CDM) ? (__bf16)sp[e] : (__bf16)0.f;
  }
  st8h(dst + (size_t)row * CDMP + c8, h);
}

// ---------------- weight transposes (fused) ----------------
struct WPtrs { const float* w[18]; };

__global__ __launch_bounds__(256) void trans_all_k(WPtrs P, __bf16* __restrict__ dst) {
  int wi = blockIdx.y;
  const float* W = P.w[wi];
  __bf16* WT = dst + (size_t)wi * DD * DD;
  int i = blockIdx.x * 256 + threadIdx.x;
  if (i >= DD * DD) return;
  int n = i / DD, k = i - n * DD;
  WT[i] = (__bf16)W[(size_t)k * DD + n];
}

__global__ __launch_bounds__(256) void trans_corr_k(const float* __restrict__ W,
                                                    __bf16* __restrict__ WT) {
  int i = blockIdx.x * 256 + threadIdx.x;
  if (i >= DD * CDMP) return;
  int n = i / CDMP, k = i - n * CDMP;
  WT[i] = (k < CDM) ? (__bf16)W[(size_t)k * DD + n] : (__bf16)0.f;
}

// ---------------- MFMA GEMM: OUT[M,384] = epi(A[M,K] @ W) ----------------
// m97 structure: single 32KB LDS buffer, 2 barriers per K-step (BK=64).
// EPI: 0 store, 1 relu, 2 OUT += v (in-place), 3 OUT = XRES + sigmoid(OUT)*v
// AFP32: A fp32 (reg-stage + cvt); else bf16 via global_load_lds.
// LDS [128][64] bf16 per operand, chunk(16B)-XOR swizzle: chunk = c ^ (row&7).
template <int EPI, int AFP32>
__global__ __launch_bounds__(256, 2) void gemm_k(
    const void* __restrict__ Av, const __bf16* __restrict__ WT,
    const float* __restrict__ bias, __bf16* __restrict__ OUT,
    const __bf16* __restrict__ XRES, const int* __restrict__ idx,
    const __bf16* __restrict__ zpage, int M, int K, int Kreal, int nwg) {
  __shared__ __align__(16) __bf16 sm[2][128 * 64];
  const int t = threadIdx.x;
  const int w = t >> 6, lane = t & 63;
  // bijective XCD swizzle; logical wg = m*3 + n so A-tile sharers are XCD-local
  int orig = blockIdx.x;
  int q = nwg >> 3, r = nwg & 7, xcd = orig & 7, lid = orig >> 3;
  int wg = (xcd < r ? xcd * (q + 1) : r * (q + 1) + (xcd - r) * q) + lid;
  const int m0 = (wg / 3) * 128;
  const int n0 = (wg % 3) * 128;
  const int fr = lane & 15, fq = lane >> 4;
  const int wr = (w >> 1) * 64, wc = (w & 1) * 64;

  const __bf16* bptr[4];
  const __bf16* aptr[4];
  int aadv[4];
#pragma unroll
  for (int j = 0; j < 4; ++j) {
    int rloc = w * 32 + j * 8 + (lane >> 3);
    int cch = (lane & 7) ^ (rloc & 7);
    bptr[j] = WT + (size_t)(n0 + rloc) * K + cch * 8;
    if constexpr (!AFP32) {
      int gm = m0 + rloc;
      int ar = idx ? idx[gm] : gm;
      if (ar >= 0) { aptr[j] = (const __bf16*)Av + (size_t)ar * K + cch * 8; aadv[j] = 64; }
      else { aptr[j] = zpage; aadv[j] = 0; }
    }
  }
  const float* Af = (const float*)Av;
  const int NT = K >> 6;

  f32x4 acc[4][4];
#pragma unroll
  for (int a = 0; a < 4; ++a)
#pragma unroll
    for (int b = 0; b < 4; ++b)
#pragma unroll
      for (int j = 0; j < 4; ++j) acc[a][b][j] = 0.f;

  auto stage = [&](int k0) {
    __bf16* As = sm[0];
    __bf16* Bs = sm[1];
    if constexpr (AFP32) {
#pragma unroll
      for (int p = 0; p < 4; ++p) {
        int rr = p * 32 + (t >> 3);
        int cc = t & 7;
        int kb = k0 + cc * 8;
        const float* ap = Af + (size_t)(m0 + rr) * Kreal + kb;
        float vv[8];
        if (kb + 8 <= Kreal) {
          f4 v0 = ld4(ap), v1 = ld4(ap + 4);
#pragma unroll
          for (int e = 0; e < 4; ++e) { vv[e] = v0[e]; vv[4 + e] = v1[e]; }
        } else {
#pragma unroll
          for (int e = 0; e < 8; ++e) vv[e] = (kb + e < Kreal) ? ap[e] : 0.f;
        }
        bf16x8 h;
#pragma unroll
        for (int e = 0; e < 8; ++e) h[e] = (__bf16)vv[e];
        *reinterpret_cast<bf16x8*>(&As[rr * 64 + (((cc ^ (rr & 7)) << 3))]) = h;
      }
    } else {
#pragma unroll
      for (int j = 0; j < 4; ++j) {
        gl_lds16(aptr[j], &As[(w * 32 + j * 8) * 64]);
        aptr[j] += aadv[j];
      }
    }
#pragma unroll
    for (int j = 0; j < 4; ++j) {
      gl_lds16(bptr[j], &Bs[(w * 32 + j * 8) * 64]);
      bptr[j] += 64;
    }
  };

  auto compute = [&]() {
    const __bf16* As = sm[0];
    const __bf16* Bs = sm[1];
#pragma unroll
    for (int kk2 = 0; kk2 < 2; ++kk2) {
      bf16x8 af[4], bv[4];
#pragma unroll
      for (int mi = 0; mi < 4; ++mi) {
        int rr = wr + mi * 16 + fr;
        af[mi] = *reinterpret_cast<const bf16x8*>(
            &As[rr * 64 + (((fq + kk2 * 4) ^ (rr & 7)) << 3)]);
      }
#pragma unroll
      for (int ni = 0; ni < 4; ++ni) {
        int rr = wc + ni * 16 + fr;
        bv[ni] = *reinterpret_cast<const bf16x8*>(
            &Bs[rr * 64 + (((fq + kk2 * 4) ^ (rr & 7)) << 3)]);
      }
#pragma unroll
      for (int mi = 0; mi < 4; ++mi)
#pragma unroll
        for (int ni = 0; ni < 4; ++ni)
          acc[mi][ni] = __builtin_amdgcn_mfma_f32_16x16x32_bf16(af[mi], bv[ni],
                                                                acc[mi][ni], 0, 0, 0);
    }
  };

  for (int tt = 0; tt < NT; ++tt) {
    if (tt) __syncthreads();
    stage(tt << 6);
    __syncthreads();
    compute();
  }

#pragma unroll
  for (int mi = 0; mi < 4; ++mi)
#pragma unroll
    for (int ni = 0; ni < 4; ++ni) {
      int col = n0 + wc + ni * 16 + fr;
      float bvv = bias[col];
#pragma unroll
      for (int j = 0; j < 4; ++j) {
        int row = m0 + wr + mi * 16 + fq * 4 + j;
        size_t o = (size_t)row * DD + col;
        float v = acc[mi][ni][j] + bvv;
        if constexpr (EPI == 0) {
          OUT[o] = (__bf16)v;
        } else if constexpr (EPI == 1) {
          OUT[o] = (__bf16)fmaxf(v, 0.f);
        } else if constexpr (EPI == 2) {
          OUT[o] = (__bf16)((float)OUT[o] + v);
        } else {
          float gl = (float)OUT[o];
          float g = 1.f / (1.f + expf(-gl));
          OUT[o] = (__bf16)((float)XRES[o] + g * v);
        }
      }
    }
}

// ---------------- LayerNorm: 16 lanes per row, 16 rows/block ----------------
template <int RELU>
__global__ __launch_bounds__(256) void ln_k(const __bf16* __restrict__ x,
                                            const float* __restrict__ g,
                                            const float* __restrict__ b,
                                            __bf16* __restrict__ out) {
  int w = threadIdx.x >> 6, lane = threadIdx.x & 63;
  int s = lane & 15, qq = lane >> 4;
  int row = blockIdx.x * 16 + w * 4 + qq;
  size_t base = (size_t)row * DD;
  float v[24];
#pragma unroll
  for (int i = 0; i < 3; ++i) {
    bf16x8 h = ld8h(x + base + (s + 16 * i) * 8);
#pragma unroll
    for (int e = 0; e < 8; ++e) v[i * 8 + e] = (float)h[e];
  }
  float sm = 0.f;
#pragma unroll
  for (int i = 0; i < 24; ++i) sm += v[i];
  sm = gred16(sm);
  float mean = sm * (1.f / 384.f);
  float qs = 0.f;
#pragma unroll
  for (int i = 0; i < 24; ++i) { float d = v[i] - mean; qs += d * d; }
  qs = gred16(qs);
  float rs = rsqrtf(qs * (1.f / 384.f) + 1e-3f);
#pragma unroll
  for (int i = 0; i < 3; ++i) {
    int col = (s + 16 * i) * 8;
    f4 g0 = ld4(g + col), g1 = ld4(g + col + 4);
    f4 b0 = ld4(b + col), b1 = ld4(b + col + 4);
    bf16x8 o;
#pragma unroll
    for (int e = 0; e < 4; ++e) {
      float y0 = (v[i * 8 + e] - mean) * rs * g0[e] + b0[e];
      float y1 = (v[i * 8 + 4 + e] - mean) * rs * g1[e] + b1[e];
      if (RELU) { y0 = fmaxf(y0, 0.f); y1 = fmaxf(y1, 0.f); }
      o[e] = (__bf16)y0; o[4 + e] = (__bf16)y1;
    }
    st8h(out + base + col, o);
  }
}

// LN(net_fp32 + inp_fp32 + h_bf16)
__global__ __launch_bounds__(256) void ln3_k(const float* __restrict__ x1,
                                             const float* __restrict__ x2,
                                             const __bf16* __restrict__ x3,
                                             const float* __restrict__ g,
                                             const float* __restrict__ b,
                                             __bf16* __restrict__ out) {
  int w = threadIdx.x >> 6, lane = threadIdx.x & 63;
  int s = lane & 15, qq = lane >> 4;
  int row = blockIdx.x * 16 + w * 4 + qq;
  size_t base = (size_t)row * DD;
  float v[24];
#pragma unroll
  for (int i = 0; i < 3; ++i) {
    int col = (s + 16 * i) * 8;
    f4 a0 = ld4(x1 + base + col), a1 = ld4(x1 + base + col + 4);
    f4 c0 = ld4(x2 + base + col), c1 = ld4(x2 + base + col + 4);
    bf16x8 h = ld8h(x3 + base + col);
#pragma unroll
    for (int e = 0; e < 4; ++e) {
      v[i * 8 + e] = a0[e] + c0[e] + (float)h[e];
      v[i * 8 + 4 + e] = a1[e] + c1[e] + (float)h[4 + e];
    }
  }
  float sm = 0.f;
#pragma unroll
  for (int i = 0; i < 24; ++i) sm += v[i];
  sm = gred16(sm);
  float mean = sm * (1.f / 384.f);
  float qs = 0.f;
#pragma unroll
  for (int i = 0; i < 24; ++i) { float d = v[i] - mean; qs += d * d; }
  qs = gred16(qs);
  float rs = rsqrtf(qs * (1.f / 384.f) + 1e-3f);
#pragma unroll
  for (int i = 0; i < 3; ++i) {
    int col = (s + 16 * i) * 8;
    f4 g0 = ld4(g + col), g1 = ld4(g + col + 4);
    f4 b0 = ld4(b + col), b1 = ld4(b + col + 4);
    bf16x8 o;
#pragma unroll
    for (int e = 0; e < 4; ++e) {
      o[e] = (__bf16)((v[i * 8 + e] - mean) * rs * g0[e] + b0[e]);
      o[4 + e] = (__bf16)((v[i * 8 + 4 + e] - mean) * rs * g1[e] + b1[e]);
    }
    st8h(out + base + col, o);
  }
}

// ---------------- segment softmax via counting sort + fused block-per-group ----
__global__ __launch_bounds__(256) void hist_k(const int* __restrict__ gid,
                                              int* __restrict__ cnt, int n) {
  int i = blockIdx.x * 256 + threadIdx.x;
  if (i < n) atomicAdd(&cnt[gid[i]], 1);
}

// exclusive scan of cnt[0..G) -> off[0..G], single block of 256 threads
__global__ __launch_bounds__(256) void scan_k(const int* __restrict__ cnt,
                                              int* __restrict__ off, int G) {
  __shared__ int ls[256];
  int t = threadIdx.x;
  int per = G / 256;
  int base = t * per;
  int s = 0;
  for (int i = 0; i < per; ++i) s += cnt[base + i];
  ls[t] = s;
  __syncthreads();
  for (int o = 1; o < 256; o <<= 1) {
    int v = (t >= o) ? ls[t - o] : 0;
    __syncthreads();
    ls[t] += v;
    __syncthreads();
  }
  int run = (t == 0) ? 0 : ls[t - 1];
  for (int i = 0; i < per; ++i) {
    off[base + i] = run;
    run += cnt[base + i];
  }
  if (t == 255) off[G] = run;
}

__global__ __launch_bounds__(256) void scatter_k(const int* __restrict__ gid,
                                                 const int* __restrict__ off,
                                                 int* __restrict__ cur,
                                                 int* __restrict__ rows, int n) {
  int i = blockIdx.x * 256 + threadIdx.x;
  if (i >= n) return;
  int g = gid[i];
  int p = atomicAdd(&cur[g], 1);
  rows[off[g] + p] = i;
}

// one block per group, 384 threads = one per column
__global__ __launch_bounds__(384) void segagg_k(const __bf16* __restrict__ L,
                                                const __bf16* __restrict__ Ft,
                                                const int* __restrict__ rows,
                                                const int* __restrict__ off,
                                                float* __restrict__ yb) {
  int g = blockIdx.x;
  int c = threadIdx.x;
  int s = off[g], e = off[g + 1];
  float mx = -3.0e38f;
  for (int p = s; p < e; ++p) {
    int r = rows[p];
    mx = fmaxf(mx, (float)L[(size_t)r * DD + c]);
  }
  float num = 0.f, den = 0.f;
  for (int p = s; p < e; ++p) {
    int r = rows[p];
    float lv = (float)L[(size_t)r * DD + c];
    float fv = (float)Ft[(size_t)r * DD + c];
    float ev = expf(lv - mx);
    den += ev;
    num += fv * ev;
  }
  yb[(size_t)g * DD + c] = num / (den + 1e-12f);
}

__global__ __launch_bounds__(256) void addgather_k(__bf16* __restrict__ X,
                                                   const __bf16* __restrict__ z,
                                                   const int* __restrict__ gid) {
  int i = blockIdx.x * 256 + threadIdx.x;
  int row = i / 48, c = (i - row * 48) * 8;
  int g = gid[row];
  size_t lo = (size_t)row * DD + c;
  bf16x8 a = ld8h(X + lo);
  bf16x8 zz = ld8h(z + (size_t)g * DD + c);
  bf16x8 o;
#pragma unroll
  for (int e = 0; e < 8; ++e) o[e] = (__bf16)((float)a[e] + (float)zz[e]);
  st8h(X + lo, o);
}

// ---------------- final: net fp32 out + d/w heads ----------------
__global__ __launch_bounds__(256) void final_k(const __bf16* __restrict__ net,
                                               const float* __restrict__ dw,
                                               const float* __restrict__ db,
                                               const float* __restrict__ ww,
                                               const float* __restrict__ wb,
                                               float* __restrict__ out) {
  int w = threadIdx.x >> 6, lane = threadIdx.x & 63;
  int s = lane & 15, qq = lane >> 4;
  int row = blockIdx.x * 16 + w * 4 + qq;
  size_t base = (size_t)row * DD;
  float d0 = 0, d1 = 0, w0 = 0, w1 = 0;
#pragma unroll
  for (int i = 0; i < 3; ++i) {
    int col = (s + 16 * i) * 8;
    bf16x8 h = ld8h(net + base + col);
    f4 o0, o1;
#pragma unroll
    for (int e = 0; e < 4; ++e) {
      float x0 = (float)h[e], x1 = (float)h[4 + e];
      o0[e] = x0; o1[e] = x1;
      float r0 = fmaxf(x0, 0.f), r1 = fmaxf(x1, 0.f);
      int c0 = col + e, c1 = col + 4 + e;
      d0 += r0 * dw[2 * c0] + r1 * dw[2 * c1];
      d1 += r0 * dw[2 * c0 + 1] + r1 * dw[2 * c1 + 1];
      w0 += r0 * ww[2 * c0] + r1 * ww[2 * c1];
      w1 += r0 * ww[2 * c0 + 1] + r1 * ww[2 * c1 + 1];
    }
    st4(out + base + col, o0);
    st4(out + base + col + 4, o1);
  }
  d0 = gred16(d0); d1 = gred16(d1); w0 = gred16(w0); w1 = gred16(w1);
  if (s == 0) {
    float* outd = out + (size_t)NR * DD;
    float* outw = outd + (size_t)NR * 2;
    outd[2 * row] = d0 + db[0];
    outd[2 * row + 1] = d1 + db[1];
    outw[2 * row] = 1.f / (1.f + expf(-(w0 + wb[0])));
    outw[2 * row + 1] = 1.f / (1.f + expf(-(w1 + wb[1])));
  }
}

extern "C" void kernel_launch(void* const* d_in, const int* in_sizes, int n_in,
                              void* d_out, int out_size, void* d_ws, size_t ws_size,
                              hipStream_t stream) {
  const float* in_net = (const float*)d_in[0];
  const float* in_inp = (const float*)d_in[1];
  const float* in_corr = (const float*)d_in[2];
  const int* nix = (const int*)d_in[3];
  const int* njx = (const int*)d_in[4];
  const int* ukk = (const int*)d_in[5];
  const int* ujk = (const int*)d_in[6];
  auto F = [&](int i) { return (const float*)d_in[i]; };

  constexpr size_t MiB = 1024 * 1024;
  constexpr size_t SZ_ACT = (size_t)NR * DD * 2;        // 24 MiB bf16 act
  char* ws = (char*)d_ws;
  // region X (60 MiB): corr-bf16 [NR][896] (56 MiB) early; later T2b|Fb|zb|yb
  __bf16* Xc = (__bf16*)(ws);                           // corr bf16, transient
  __bf16* T2b = (__bf16*)(ws);
  __bf16* Fb = (__bf16*)(ws + SZ_ACT);
  __bf16* zb = (__bf16*)(ws + 2 * SZ_ACT);              // 3 MiB
  float* yb = (float*)(ws + 2 * SZ_ACT + 3 * MiB);      // 6 MiB -> ends at 57 MiB
  __bf16* T1b = (__bf16*)(ws + 60 * MiB);               // 24 MiB
  char* p = ws + 84 * MiB;
  int* rows = (int*)p; p += (size_t)NR * 4;             // 128 KB
  int* off = (int*)p; p += 32768;                       // 8192 ints
  int* cnt = (int*)p; p += 16384;
  int* curb = (int*)p; p += 16384;
  __bf16* wt_all = (__bf16*)p; p += (size_t)18 * DD * DD * 2;
  __bf16* wt_corr1 = (__bf16*)p; p += (size_t)DD * CDMP * 2;
  __bf16* zpage = (__bf16*)p;

  const int widx[18] = {17, 19, 21, 23, 25, 27, 29, 31, 33, 35, 39, 41, 43, 47, 49, 51, 9, 13};
  WPtrs P;
  for (int i = 0; i < 18; ++i) P.w[i] = F(widx[i]);
  auto WTp = [&](int i) { return wt_all + (size_t)i * DD * DD; };

  hipMemsetAsync(zpage, 0, 256, stream);
  trans_all_k<<<dim3(576, 18), 256, 0, stream>>>(P, wt_all);
  trans_corr_k<<<1344, 256, 0, stream>>>(F(7), wt_corr1);
  corr2bf16_k<<<NR * 112 / 256, 256, 0, stream>>>(in_corr, Xc);

  auto GEMM = [&](int epi, int afp32, const void* A, const __bf16* WT, const float* bias,
                  __bf16* OUT, const __bf16* XRES, const int* idx, int M, int Kp, int Kr) {
    int nwg = (M / 128) * 3;
    dim3 g(nwg), b(256);
    if (afp32) {
      gemm_k<0, 1><<<g, b, 0, stream>>>(A, WT, bias, OUT, XRES, idx, zpage, M, Kp, Kr, nwg);
    } else {
      switch (epi) {
        case 0: gemm_k<0, 0><<<g, b, 0, stream>>>(A, WT, bias, OUT, XRES, idx, zpage, M, Kp, Kr, nwg); break;
        case 1: gemm_k<1, 0><<<g, b, 0, stream>>>(A, WT, bias, OUT, XRES, idx, zpage, M, Kp, Kr, nwg); break;
        case 2: gemm_k<2, 0><<<g, b, 0, stream>>>(A, WT, bias, OUT, XRES, idx, zpage, M, Kp, Kr, nwg); break;
        default: gemm_k<3, 0><<<g, b, 0, stream>>>(A, WT, bias, OUT, XRES, idx, zpage, M, Kp, Kr, nwg); break;
      }
    }
  };

  // fused segment softmax-aggregation: build rowlists, then one block/group
  auto SEGAGG = [&](const int* gid, int G, const __bf16* L, const __bf16* Ft) {
    hipMemsetAsync(cnt, 0, (size_t)G * 4, stream);
    hipMemsetAsync(curb, 0, (size_t)G * 4, stream);
    hist_k<<<NR / 256, 256, 0, stream>>>(gid, cnt, NR);
    scan_k<<<1, 256, 0, stream>>>(cnt, off, G);
    scatter_k<<<NR / 256, 256, 0, stream>>>(gid, off, curb, rows, NR);
    segagg_k<<<G, 384, 0, stream>>>(L, Ft, rows, off, yb);
  };

  const int LNG = NR / 16;
  const int SEGB = NR * 48 / 256;

  // corr encoder (Xc read here; T2b region reused only after this completes)
  GEMM(1, 0, Xc, wt_corr1, F(8), T1b, nullptr, nullptr, NR, CDMP, CDMP);
  GEMM(0, 0, T1b, WTp(16), F(10), T2b, nullptr, nullptr, NR, DD, DD);
  ln_k<1><<<LNG, 256, 0, stream>>>(T2b, F(11), F(12), T1b);
  GEMM(0, 0, T1b, WTp(17), F(14), T2b, nullptr, nullptr, NR, DD, DD);
  // net2 = LN(net + inp + h)
  ln3_k<<<LNG, 256, 0, stream>>>(in_net, in_inp, T2b, F(15), F(16), T1b);
  // c1
  GEMM(1, 0, T1b, WTp(0), F(18), T2b, nullptr, nix, NR, DD, DD);
  GEMM(2, 0, T2b, WTp(1), F(20), T1b, nullptr, nullptr, NR, DD, DD);  // net3
  // c2
  GEMM(1, 0, T1b, WTp(2), F(22), T2b, nullptr, njx, NR, DD, DD);
  GEMM(2, 0, T2b, WTp(3), F(24), T1b, nullptr, nullptr, NR, DD, DD);  // net4
  // kk soft-agg (G=4096)
  GEMM(0, 0, T1b, WTp(5), F(28), T2b, nullptr, nullptr, NR, DD, DD);  // logits
  GEMM(0, 0, T1b, WTp(4), F(26), Fb, nullptr, nullptr, NR, DD, DD);   // feats
  SEGAGG(ukk, 4096, T2b, Fb);
  GEMM(0, 1, yb, WTp(6), F(30), zb, nullptr, nullptr, 4096, DD, DD);
  addgather_k<<<SEGB, 256, 0, stream>>>(T1b, zb, ukk);                // net5
  // ij soft-agg (G=512)
  GEMM(0, 0, T1b, WTp(8), F(34), T2b, nullptr, nullptr, NR, DD, DD);
  GEMM(0, 0, T1b, WTp(7), F(32), Fb, nullptr, nullptr, NR, DD, DD);
  SEGAGG(ujk, 512, T2b, Fb);
  GEMM(0, 1, yb, WTp(9), F(36), zb, nullptr, nullptr, 512, DD, DD);
  addgather_k<<<SEGB, 256, 0, stream>>>(T1b, zb, ujk);                // net6
  // gated residual 1
  ln_k<0><<<LNG, 256, 0, stream>>>(T1b, F(37), F(38), T2b);           // x = LN(net6)
  GEMM(0, 0, T2b, WTp(10), F(40), Fb, nullptr, nullptr, NR, DD, DD);  // gate logits
  GEMM(1, 0, T2b, WTp(11), F(42), T1b, nullptr, nullptr, NR, DD, DD); // relu hidden
  GEMM(3, 0, T1b, WTp(12), F(44), Fb, T2b, nullptr, NR, DD, DD);      // Fb = net7
  // gated residual 2
  ln_k<0><<<LNG, 256, 0, stream>>>(Fb, F(45), F(46), T1b);            // x = LN(net7)
  GEMM(0, 0, T1b, WTp(13), F(48), T2b, nullptr, nullptr, NR, DD, DD);
  GEMM(1, 0, T1b, WTp(14), F(50), Fb, nullptr, nullptr, NR, DD, DD);
  GEMM(3, 0, Fb, WTp(15), F(52), T2b, T1b, nullptr, NR, DD, DD);      // T2b = net9
  // outputs
  final_k<<<LNG, 256, 0, stream>>>(T2b, F(53), F(54), F(55), F(56), (float*)d_out);
}